// Round 8
// baseline (147.543 us; speedup 1.0000x reference)
//
#include <hip/hip_runtime.h>

// ---------------------------------------------------------------------------
// DeepLagrangianNetwork head — round 12: all-MFMA, folded layer-1, lean VGPR.
// Ledger: R10 (all-MFMA) had the lowest VALU-work but VGPR 132 killed
// occupancy; R11 (MFMA heads) proved hA costs 16 regs; R11's grid-stride
// loop caused weight-prep remat (VGPR 56, VALUBusy 75%). This round:
//   - layer-1 in ONE 16x16x32 MFMA per tile via k-slot packing:
//       A quad0: k0-3=W1hi(row nu), k4=b1hi, k5=b1lo; quad1: k8-11=W1lo,
//       k12-15=W1hi; quads2-3 zero.
//       B quad0: k0-3=xhi, k4=k5=1.0;  quad1: k8-11=xhi, k12-15=xlo.
//       => W1hi*xhi + W1lo*xhi + W1hi*xlo + b1  (residual ~2^-18; same fold
//       R10 verified).  16 A-VGPRs, 4 MFMA/it (was 32 regs / 12 MFMA).
//   - layer-2 + MFMA heads exactly as R11 (nu-permuted W2, identity handoff,
//     hi/lo-split head weights) — verified numerics, absmax 0.0078125.
//   - NO LDS, NO barriers, NO shuffles, NO grid-stride loop: one 256-row
//     group per block (straight-line => no remat incentive), 4096 blocks.
//   - NO launch_bounds min-waves clause (64-VGPR clamp + spill; rounds 6,8).
// Permutation (verified by R10/R11 passes):
//   nu(mt,m) = 32*(mt>>1) + 8*(m>>2) + 4*(mt&1) + (m&3)
//   => lrelu'd C of tile mt, cvt_pk-packed, lands neuron k in k-slot k of the
//      next MFMA's B fragment (identity handoff, registers only).
// Fragment layouts (m89/m120-verified):
//   A[m=lane&15][k=(lane>>4)*8+j]   B[k=(lane>>4)*8+j][n=lane&15]
//   C: col(n)=lane&15, row(m)=(lane>>4)*4+reg
// ---------------------------------------------------------------------------

typedef __attribute__((ext_vector_type(8))) short bf16x8;
typedef __attribute__((ext_vector_type(4))) float f32x4;
typedef __attribute__((ext_vector_type(2))) float f32x2;

#define BLOCK_THREADS  256      // 4 waves; each wave owns 64 rows
#define ROWS_PER_GROUP 256

__device__ __forceinline__ float lrelu(float a) {
    return fmaxf(a, 0.01f * a);     // exact leaky_relu(0.01)
}

__device__ __forceinline__ f32x2 lrelu2(f32x2 a) {
    return __builtin_elementwise_max(a, a * 0.01f);
}

__device__ __forceinline__ float softplus(float v) {
    return fmaxf(v, 0.0f) + log1pf(expf(-fabsf(v)));   // jax.nn.softplus
}

// two fp32 -> packed bf16x2 (hardware RNE), 1 VALU op.
__device__ __forceinline__ unsigned cvt_pk_bf16(float lo, float hi) {
    unsigned r;
    asm("v_cvt_pk_bf16_f32 %0, %1, %2" : "=v"(r) : "v"(lo), "v"(hi));
    return r;
}

// residual v - float(bf16_hi(v)), where pk holds the packed hi pair
__device__ __forceinline__ float lo_of(float v, unsigned pk, bool hi_half) {
    const float h = __uint_as_float(hi_half ? (pk & 0xFFFF0000u) : (pk << 16));
    return v - h;
}

__global__ __launch_bounds__(BLOCK_THREADS) void dln_mfma(
    const float* __restrict__ x,
    const float* __restrict__ W1,  const float* __restrict__ b1,
    const float* __restrict__ W2,  const float* __restrict__ b2,
    const float* __restrict__ WLd, const float* __restrict__ bLd,
    const float* __restrict__ WLo, const float* __restrict__ bLo,
    float* __restrict__ out)
{
    const int tid  = threadIdx.x;
    const int lane = tid & 63;
    const int wv   = tid >> 6;          // wave id 0..3
    const int quad = lane >> 4;         // 0..3
    const int c    = lane & 15;         // 0..15

    const int wbase = blockIdx.x * ROWS_PER_GROUP + wv * 64;

    // ---- x loads first (cold HBM): 4 independent float4 in flight --------
    float4 xv[4];
#pragma unroll
    for (int it = 0; it < 4; ++it)
        xv[it] = ((const float4*)x)[wbase + it * 16 + c];

    // ---- layer-1 A fragments: folded {W1hi, W1lo, b1hi, b1lo}, 1/mt ------
    bf16x8 a1[4];
#pragma unroll
    for (int mt = 0; mt < 4; ++mt) {
        const int nu = 32 * (mt >> 1) + 8 * (c >> 2) + 4 * (mt & 1) + (c & 3);
        const float4 w = *(const float4*)(W1 + 4 * nu);   // W1 is (64,4) row-major
        const float bb = b1[nu];
        const unsigned h01 = cvt_pk_bf16(w.x, w.y);
        const unsigned h23 = cvt_pk_bf16(w.z, w.w);
        uint4 u = make_uint4(0u, 0u, 0u, 0u);
        if (quad == 0) {
            // k0-3 = W1hi, k4 = b1hi, k5 = b1lo
            const unsigned t = cvt_pk_bf16(bb, 0.0f);
            const float bl = bb - __uint_as_float(t << 16);
            u.x = h01; u.y = h23;
            u.z = cvt_pk_bf16(bb, bl);
        } else if (quad == 1) {
            // k8-11 = W1lo, k12-15 = W1hi
            u.x = cvt_pk_bf16(lo_of(w.x, h01, false), lo_of(w.y, h01, true));
            u.y = cvt_pk_bf16(lo_of(w.z, h23, false), lo_of(w.w, h23, true));
            u.z = h01; u.w = h23;
        }
        a1[mt] = __builtin_bit_cast(bf16x8, u);
    }

    // ---- layer-2 A fragments from nu-permuted W2 rows + permuted b2 ------
    bf16x8 afrag[4][2];
    f32x4 b2v[4];
#pragma unroll
    for (int mt = 0; mt < 4; ++mt) {
        const int nu = 32 * (mt >> 1) + 8 * (c >> 2) + 4 * (mt & 1) + (c & 3);
        const float* wr = W2 + nu * 64 + 8 * quad;
#pragma unroll
        for (int s = 0; s < 2; ++s) {
            const float4 f0 = *(const float4*)(wr + 32 * s);
            const float4 f1 = *(const float4*)(wr + 32 * s + 4);
            uint4 u;
            u.x = cvt_pk_bf16(f0.x, f0.y);
            u.y = cvt_pk_bf16(f0.z, f0.w);
            u.z = cvt_pk_bf16(f1.x, f1.y);
            u.w = cvt_pk_bf16(f1.z, f1.w);
            afrag[mt][s] = __builtin_bit_cast(bf16x8, u);
        }
        b2v[mt] = *(const f32x4*)(b2 + 32 * (mt >> 1) + 4 * (mt & 1) + 8 * quad);
    }

    // ---- head A fragments: rows {WLd0, WLd1, WLo, 0...}, hi/lo split -----
    bf16x8 hA[2][2];    // [k-chunk s][hi=0 / lo=1]
    {
        const float* hw = (c == 0) ? WLd : (c == 1) ? (WLd + 64) : WLo;
#pragma unroll
        for (int s = 0; s < 2; ++s) {
            uint4 uh = make_uint4(0u, 0u, 0u, 0u);
            uint4 ul = make_uint4(0u, 0u, 0u, 0u);
            if (c < 3) {
                const float* p = hw + 32 * s + 8 * quad;
                const float4 f0 = *(const float4*)(p);
                const float4 f1 = *(const float4*)(p + 4);
                uh.x = cvt_pk_bf16(f0.x, f0.y);
                uh.y = cvt_pk_bf16(f0.z, f0.w);
                uh.z = cvt_pk_bf16(f1.x, f1.y);
                uh.w = cvt_pk_bf16(f1.z, f1.w);
                ul.x = cvt_pk_bf16(lo_of(f0.x, uh.x, false), lo_of(f0.y, uh.x, true));
                ul.y = cvt_pk_bf16(lo_of(f0.z, uh.y, false), lo_of(f0.w, uh.y, true));
                ul.z = cvt_pk_bf16(lo_of(f1.x, uh.z, false), lo_of(f1.y, uh.z, true));
                ul.w = cvt_pk_bf16(lo_of(f1.z, uh.w, false), lo_of(f1.w, uh.w, true));
            }
            hA[s][0] = __builtin_bit_cast(bf16x8, uh);
            hA[s][1] = __builtin_bit_cast(bf16x8, ul);
        }
    }
    const f32x4 hinit = (quad == 0)
        ? (f32x4){bLd[0], bLd[1], bLo[0], 0.0f}
        : (f32x4){0.0f, 0.0f, 0.0f, 0.0f};

    // ---- 4 independent row-tiles: L1 MFMA -> L2 MFMA -> head MFMA --------
#pragma unroll
    for (int it = 0; it < 4; ++it) {
        // layer-1 B fragment: folded {xhi, 1.0, xlo} per quad
        const unsigned xh01 = cvt_pk_bf16(xv[it].x, xv[it].y);
        const unsigned xh23 = cvt_pk_bf16(xv[it].z, xv[it].w);
        uint4 ub = make_uint4(0u, 0u, 0u, 0u);
        if (quad == 0) {
            ub.x = xh01; ub.y = xh23; ub.z = 0x3F803F80u;   // k4=k5=1.0
        } else if (quad == 1) {
            ub.x = xh01; ub.y = xh23;
            ub.z = cvt_pk_bf16(lo_of(xv[it].x, xh01, false), lo_of(xv[it].y, xh01, true));
            ub.w = cvt_pk_bf16(lo_of(xv[it].z, xh23, false), lo_of(xv[it].w, xh23, true));
        }
        const bf16x8 bx = __builtin_bit_cast(bf16x8, ub);

        // layer-1: one MFMA per tile, 4 independent
        f32x4 acc1[4];
#pragma unroll
        for (int mt = 0; mt < 4; ++mt)
            acc1[mt] = __builtin_amdgcn_mfma_f32_16x16x32_bf16(
                a1[mt], bx, (f32x4){0.0f, 0.0f, 0.0f, 0.0f}, 0, 0, 0);

        // lrelu + pack: identity handoff to layer-2 B fragments
        uint4 u0, u1;
        {
            const f32x2 p0 = lrelu2((f32x2){acc1[0][0], acc1[0][1]});
            const f32x2 p1 = lrelu2((f32x2){acc1[0][2], acc1[0][3]});
            const f32x2 p2 = lrelu2((f32x2){acc1[1][0], acc1[1][1]});
            const f32x2 p3 = lrelu2((f32x2){acc1[1][2], acc1[1][3]});
            const f32x2 p4 = lrelu2((f32x2){acc1[2][0], acc1[2][1]});
            const f32x2 p5 = lrelu2((f32x2){acc1[2][2], acc1[2][3]});
            const f32x2 p6 = lrelu2((f32x2){acc1[3][0], acc1[3][1]});
            const f32x2 p7 = lrelu2((f32x2){acc1[3][2], acc1[3][3]});
            u0.x = cvt_pk_bf16(p0[0], p0[1]);
            u0.y = cvt_pk_bf16(p1[0], p1[1]);
            u0.z = cvt_pk_bf16(p2[0], p2[1]);
            u0.w = cvt_pk_bf16(p3[0], p3[1]);
            u1.x = cvt_pk_bf16(p4[0], p4[1]);
            u1.y = cvt_pk_bf16(p5[0], p5[1]);
            u1.z = cvt_pk_bf16(p6[0], p6[1]);
            u1.w = cvt_pk_bf16(p7[0], p7[1]);
        }
        const bf16x8 bf0 = __builtin_bit_cast(bf16x8, u0);
        const bf16x8 bf1 = __builtin_bit_cast(bf16x8, u1);

        // layer-2: 4 tiles x 2 MFMA; lrelu + pack -> head B fragments
        uint4 v0, v1;
#pragma unroll
        for (int mt = 0; mt < 4; ++mt) {
            f32x4 acc = b2v[mt];                // permuted bias pre-load
            acc = __builtin_amdgcn_mfma_f32_16x16x32_bf16(afrag[mt][0], bf0, acc, 0, 0, 0);
            acc = __builtin_amdgcn_mfma_f32_16x16x32_bf16(afrag[mt][1], bf1, acc, 0, 0, 0);
            const f32x2 hlo = lrelu2((f32x2){acc[0], acc[1]});
            const f32x2 hhi = lrelu2((f32x2){acc[2], acc[3]});
            const unsigned pa = cvt_pk_bf16(hlo[0], hlo[1]);
            const unsigned pb = cvt_pk_bf16(hhi[0], hhi[1]);
            if (mt == 0)      { v0.x = pa; v0.y = pb; }
            else if (mt == 1) { v0.z = pa; v0.w = pb; }
            else if (mt == 2) { v1.x = pa; v1.y = pb; }
            else              { v1.z = pa; v1.w = pb; }
        }
        const bf16x8 bh0 = __builtin_bit_cast(bf16x8, v0);
        const bf16x8 bh1 = __builtin_bit_cast(bf16x8, v1);

        // heads: two parallel 2-MFMA chains (hi terms / lo terms)
        f32x4 ha = hinit;
        f32x4 hb = (f32x4){0.0f, 0.0f, 0.0f, 0.0f};
        ha = __builtin_amdgcn_mfma_f32_16x16x32_bf16(hA[0][0], bh0, ha, 0, 0, 0);
        hb = __builtin_amdgcn_mfma_f32_16x16x32_bf16(hA[0][1], bh0, hb, 0, 0, 0);
        ha = __builtin_amdgcn_mfma_f32_16x16x32_bf16(hA[1][0], bh1, ha, 0, 0, 0);
        hb = __builtin_amdgcn_mfma_f32_16x16x32_bf16(hA[1][1], bh1, hb, 0, 0, 0);

        // quad-0 lanes hold rows m=0,1,2 (Ld0, Ld1, Lo) for batch row it*16+c
        if (quad == 0) {
            const float ld0 = softplus(ha[0] + hb[0]);
            const float ld1 = softplus(ha[1] + hb[1]);
            const float lo  = ha[2] + hb[2];
            float4 o;
            o.x = fmaf(ld0, ld0, 1e-9f);                  // H00
            o.y = ld0 * lo;                               // H01
            o.z = o.y;                                    // H10
            o.w = fmaf(lo, lo, fmaf(ld1, ld1, 1e-9f));    // H11
            reinterpret_cast<float4*>(out)[wbase + it * 16 + c] = o;
        }
    }
}

// ---- scalar fallback for tail rows (nrows % 256) --------------------------
__global__ __launch_bounds__(256) void dln_tail(
    const float* __restrict__ x,
    const float* __restrict__ W1,  const float* __restrict__ b1,
    const float* __restrict__ W2,  const float* __restrict__ b2,
    const float* __restrict__ WLd, const float* __restrict__ bLd,
    const float* __restrict__ WLo, const float* __restrict__ bLo,
    float* __restrict__ out, int row0, int nrows)
{
    const int row = row0 + blockIdx.x * 256 + threadIdx.x;
    if (row >= nrows) return;
    const float4 qv = reinterpret_cast<const float4*>(x)[row];
    float h1[64];
#pragma unroll
    for (int j = 0; j < 64; ++j) {
        float a = b1[j];
        a = fmaf(qv.x, W1[4 * j + 0], a);
        a = fmaf(qv.y, W1[4 * j + 1], a);
        a = fmaf(qv.z, W1[4 * j + 2], a);
        a = fmaf(qv.w, W1[4 * j + 3], a);
        h1[j] = lrelu(a);
    }
    float ld0 = bLd[0], ld1 = bLd[1], lo = bLo[0];
#pragma unroll 4
    for (int j = 0; j < 64; ++j) {
        float a0 = b2[j], a1 = 0.0f;
        const float* w = W2 + 64 * j;
#pragma unroll
        for (int k = 0; k < 64; k += 2) {
            a0 = fmaf(h1[k],     w[k],     a0);
            a1 = fmaf(h1[k + 1], w[k + 1], a1);
        }
        const float a = lrelu(a0 + a1);
        ld0 = fmaf(a, WLd[j],      ld0);
        ld1 = fmaf(a, WLd[64 + j], ld1);
        lo  = fmaf(a, WLo[j],      lo);
    }
    ld0 = softplus(ld0);
    ld1 = softplus(ld1);
    float4 o;
    o.x = fmaf(ld0, ld0, 1e-9f);
    o.y = ld0 * lo;
    o.z = o.y;
    o.w = fmaf(lo, lo, fmaf(ld1, ld1, 1e-9f));
    reinterpret_cast<float4*>(out)[row] = o;
}

extern "C" void kernel_launch(void* const* d_in, const int* in_sizes, int n_in,
                              void* d_out, int out_size, void* d_ws, size_t ws_size,
                              hipStream_t stream)
{
    const float* x   = (const float*)d_in[0];
    const float* W1  = (const float*)d_in[1];
    const float* b1  = (const float*)d_in[2];
    const float* W2  = (const float*)d_in[3];
    const float* b2  = (const float*)d_in[4];
    const float* WLd = (const float*)d_in[5];
    const float* bLd = (const float*)d_in[6];
    const float* WLo = (const float*)d_in[7];
    const float* bLo = (const float*)d_in[8];
    float* out = (float*)d_out;

    const int nrows   = in_sizes[0] / 4;            // x is (nrows, 4) fp32
    const int ngroups = nrows / ROWS_PER_GROUP;
    const int nfull   = ngroups * ROWS_PER_GROUP;
    const int rem     = nrows - nfull;

    if (ngroups > 0)
        dln_mfma<<<ngroups, BLOCK_THREADS, 0, stream>>>(
            x, W1, b1, W2, b2, WLd, bLd, WLo, bLo, out);
    if (rem > 0)
        dln_tail<<<(rem + 255) / 256, 256, 0, stream>>>(
            x, W1, b1, W2, b2, WLd, bLd, WLo, bLo, out, nfull, nrows);
}

// Round 9
// 140.661 us; speedup vs baseline: 1.0489x; 1.0489x over previous
//
#include <hip/hip_runtime.h>

// ---------------------------------------------------------------------------
// DeepLagrangianNetwork head — round 13: R12 inner loop + R10 amortization.
// Ledger synthesis:
//   - R12 proved the cheapest verified inner loop (folded 1-MFMA layer-1,
//     MFMA heads): ~320 VALU + 64 MFMA per wave-group, absmax exact.
//   - R12's regression was prep-per-block (4096x). R10 proved grid-stride
//     1024x4 amortizes prep; its failure was VGPR 132. R12's persistent set
//     is only ~80 regs -> fits.
//   - R11 proved the compiler remats weight prep inside grid-stride loops
//     when it wants a lean allocation. Countermeasure: opaque
//     asm volatile("" : "+v"(frag)) pinning at loop top (rule-17 trick) —
//     fragments become asm-defined, so they can be neither rematerialized
//     nor sunk; they must stay resident.
//   - NO launch_bounds min-waves clause (64-VGPR clamp + spill; R6, R8).
//   - NO LDS, NO barriers, NO shuffles.
// dur tracks total VALU issue across all non-spill rounds (VALU-work product
// 29-54 us-equiv <-> dur 51-77 us): this round minimizes total VALU issue at
// >=4 waves/SIMD occupancy.
// Permutation (verified R10/R11/R12 passes):
//   nu(mt,m) = 32*(mt>>1) + 8*(m>>2) + 4*(mt&1) + (m&3)
//   => lrelu'd C of tile mt, cvt_pk-packed, lands neuron k in k-slot k of the
//      next MFMA's B fragment (identity handoff, registers only).
// Layer-1 fold (verified R12): one 16x16x32 MFMA computes
//   W1hi*xhi + W1lo*xhi + W1hi*xlo + b1 via k-slot packing (residual ~2^-18).
// Fragment layouts (m89/m120-verified):
//   A[m=lane&15][k=(lane>>4)*8+j]   B[k=(lane>>4)*8+j][n=lane&15]
//   C: col(n)=lane&15, row(m)=(lane>>4)*4+reg
// ---------------------------------------------------------------------------

typedef __attribute__((ext_vector_type(8))) short bf16x8;
typedef __attribute__((ext_vector_type(4))) float f32x4;
typedef __attribute__((ext_vector_type(2))) float f32x2;

#define BLOCK_THREADS  256      // 4 waves; each wave owns 64 rows per group
#define GRID_BLOCKS    1024     // 4 blocks/CU, single generation, grid-stride
#define ROWS_PER_GROUP 256

__device__ __forceinline__ float lrelu(float a) {
    return fmaxf(a, 0.01f * a);     // exact leaky_relu(0.01)
}

__device__ __forceinline__ f32x2 lrelu2(f32x2 a) {
    return __builtin_elementwise_max(a, a * 0.01f);
}

__device__ __forceinline__ float softplus(float v) {
    return fmaxf(v, 0.0f) + log1pf(expf(-fabsf(v)));   // jax.nn.softplus
}

// two fp32 -> packed bf16x2 (hardware RNE), 1 VALU op.
__device__ __forceinline__ unsigned cvt_pk_bf16(float lo, float hi) {
    unsigned r;
    asm("v_cvt_pk_bf16_f32 %0, %1, %2" : "=v"(r) : "v"(lo), "v"(hi));
    return r;
}

// residual v - float(bf16_hi(v)), where pk holds the packed hi pair
__device__ __forceinline__ float lo_of(float v, unsigned pk, bool hi_half) {
    const float h = __uint_as_float(hi_half ? (pk & 0xFFFF0000u) : (pk << 16));
    return v - h;
}

__global__ __launch_bounds__(BLOCK_THREADS) void dln_mfma(
    const float* __restrict__ x,
    const float* __restrict__ W1,  const float* __restrict__ b1,
    const float* __restrict__ W2,  const float* __restrict__ b2,
    const float* __restrict__ WLd, const float* __restrict__ bLd,
    const float* __restrict__ WLo, const float* __restrict__ bLo,
    float* __restrict__ out, int ngroups)
{
    const int tid  = threadIdx.x;
    const int lane = tid & 63;
    const int wv   = tid >> 6;          // wave id 0..3
    const int quad = lane >> 4;         // 0..3
    const int c    = lane & 15;         // 0..15

    // ---- prep ONCE per wave (amortized over ~4 groups) --------------------
    // layer-1 A fragments: folded {W1hi, W1lo, b1hi, b1lo}, one per mt
    bf16x8 a1[4];
#pragma unroll
    for (int mt = 0; mt < 4; ++mt) {
        const int nu = 32 * (mt >> 1) + 8 * (c >> 2) + 4 * (mt & 1) + (c & 3);
        const float4 w = *(const float4*)(W1 + 4 * nu);   // W1 is (64,4) row-major
        const float bb = b1[nu];
        const unsigned h01 = cvt_pk_bf16(w.x, w.y);
        const unsigned h23 = cvt_pk_bf16(w.z, w.w);
        uint4 u = make_uint4(0u, 0u, 0u, 0u);
        if (quad == 0) {
            // k0-3 = W1hi, k4 = b1hi, k5 = b1lo
            const unsigned t = cvt_pk_bf16(bb, 0.0f);
            const float bl = bb - __uint_as_float(t << 16);
            u.x = h01; u.y = h23;
            u.z = cvt_pk_bf16(bb, bl);
        } else if (quad == 1) {
            // k8-11 = W1lo, k12-15 = W1hi
            u.x = cvt_pk_bf16(lo_of(w.x, h01, false), lo_of(w.y, h01, true));
            u.y = cvt_pk_bf16(lo_of(w.z, h23, false), lo_of(w.w, h23, true));
            u.z = h01; u.w = h23;
        }
        a1[mt] = __builtin_bit_cast(bf16x8, u);
    }

    // layer-2 A fragments from nu-permuted W2 rows + permuted b2
    bf16x8 afrag[4][2];
    f32x4 b2v[4];
#pragma unroll
    for (int mt = 0; mt < 4; ++mt) {
        const int nu = 32 * (mt >> 1) + 8 * (c >> 2) + 4 * (mt & 1) + (c & 3);
        const float* wr = W2 + nu * 64 + 8 * quad;
#pragma unroll
        for (int s = 0; s < 2; ++s) {
            const float4 f0 = *(const float4*)(wr + 32 * s);
            const float4 f1 = *(const float4*)(wr + 32 * s + 4);
            uint4 u;
            u.x = cvt_pk_bf16(f0.x, f0.y);
            u.y = cvt_pk_bf16(f0.z, f0.w);
            u.z = cvt_pk_bf16(f1.x, f1.y);
            u.w = cvt_pk_bf16(f1.z, f1.w);
            afrag[mt][s] = __builtin_bit_cast(bf16x8, u);
        }
        b2v[mt] = *(const f32x4*)(b2 + 32 * (mt >> 1) + 4 * (mt & 1) + 8 * quad);
    }

    // head A fragments: rows {WLd0, WLd1, WLo, 0...}, hi/lo split
    bf16x8 hA[2][2];    // [k-chunk s][hi=0 / lo=1]
    {
        const float* hw = (c == 0) ? WLd : (c == 1) ? (WLd + 64) : WLo;
#pragma unroll
        for (int s = 0; s < 2; ++s) {
            uint4 uh = make_uint4(0u, 0u, 0u, 0u);
            uint4 ul = make_uint4(0u, 0u, 0u, 0u);
            if (c < 3) {
                const float* p = hw + 32 * s + 8 * quad;
                const float4 f0 = *(const float4*)(p);
                const float4 f1 = *(const float4*)(p + 4);
                uh.x = cvt_pk_bf16(f0.x, f0.y);
                uh.y = cvt_pk_bf16(f0.z, f0.w);
                uh.z = cvt_pk_bf16(f1.x, f1.y);
                uh.w = cvt_pk_bf16(f1.z, f1.w);
                ul.x = cvt_pk_bf16(lo_of(f0.x, uh.x, false), lo_of(f0.y, uh.x, true));
                ul.y = cvt_pk_bf16(lo_of(f0.z, uh.y, false), lo_of(f0.w, uh.y, true));
                ul.z = cvt_pk_bf16(lo_of(f1.x, uh.z, false), lo_of(f1.y, uh.z, true));
                ul.w = cvt_pk_bf16(lo_of(f1.z, uh.w, false), lo_of(f1.w, uh.w, true));
            }
            hA[s][0] = __builtin_bit_cast(bf16x8, uh);
            hA[s][1] = __builtin_bit_cast(bf16x8, ul);
        }
    }
    const float bld0 = bLd[0];      // uniform -> SGPR
    const float bld1 = bLd[1];
    const float blo0 = bLo[0];

    for (int grp = blockIdx.x; grp < ngroups; grp += (int)gridDim.x) {
        // ---- pin persistent fragments: no remat, no sinking (R11 lesson) -
#pragma unroll
        for (int mt = 0; mt < 4; ++mt) {
            asm volatile("" : "+v"(a1[mt]));
            asm volatile("" : "+v"(afrag[mt][0]));
            asm volatile("" : "+v"(afrag[mt][1]));
            asm volatile("" : "+v"(b2v[mt]));
        }
        asm volatile("" : "+v"(hA[0][0]));
        asm volatile("" : "+v"(hA[0][1]));
        asm volatile("" : "+v"(hA[1][0]));
        asm volatile("" : "+v"(hA[1][1]));

        const int wbase = grp * ROWS_PER_GROUP + wv * 64;

        // 4 row-tiles' x in flight
        float4 xv[4];
#pragma unroll
        for (int it = 0; it < 4; ++it)
            xv[it] = ((const float4*)x)[wbase + it * 16 + c];

        const f32x4 hinit = (quad == 0)
            ? (f32x4){bld0, bld1, blo0, 0.0f}
            : (f32x4){0.0f, 0.0f, 0.0f, 0.0f};

        // ---- 4 independent row-tiles: L1 MFMA -> L2 MFMA -> head MFMA ----
#pragma unroll
        for (int it = 0; it < 4; ++it) {
            // layer-1 B fragment: folded {xhi, 1.0, xlo} per quad
            const unsigned xh01 = cvt_pk_bf16(xv[it].x, xv[it].y);
            const unsigned xh23 = cvt_pk_bf16(xv[it].z, xv[it].w);
            uint4 ub = make_uint4(0u, 0u, 0u, 0u);
            if (quad == 0) {
                ub.x = xh01; ub.y = xh23; ub.z = 0x3F803F80u;   // k4=k5=1.0
            } else if (quad == 1) {
                ub.x = xh01; ub.y = xh23;
                ub.z = cvt_pk_bf16(lo_of(xv[it].x, xh01, false), lo_of(xv[it].y, xh01, true));
                ub.w = cvt_pk_bf16(lo_of(xv[it].z, xh23, false), lo_of(xv[it].w, xh23, true));
            }
            const bf16x8 bx = __builtin_bit_cast(bf16x8, ub);

            // layer-1: one MFMA per tile, 4 independent
            f32x4 acc1[4];
#pragma unroll
            for (int mt = 0; mt < 4; ++mt)
                acc1[mt] = __builtin_amdgcn_mfma_f32_16x16x32_bf16(
                    a1[mt], bx, (f32x4){0.0f, 0.0f, 0.0f, 0.0f}, 0, 0, 0);

            // lrelu + pack: identity handoff to layer-2 B fragments
            uint4 u0, u1;
            {
                const f32x2 p0 = lrelu2((f32x2){acc1[0][0], acc1[0][1]});
                const f32x2 p1 = lrelu2((f32x2){acc1[0][2], acc1[0][3]});
                const f32x2 p2 = lrelu2((f32x2){acc1[1][0], acc1[1][1]});
                const f32x2 p3 = lrelu2((f32x2){acc1[1][2], acc1[1][3]});
                const f32x2 p4 = lrelu2((f32x2){acc1[2][0], acc1[2][1]});
                const f32x2 p5 = lrelu2((f32x2){acc1[2][2], acc1[2][3]});
                const f32x2 p6 = lrelu2((f32x2){acc1[3][0], acc1[3][1]});
                const f32x2 p7 = lrelu2((f32x2){acc1[3][2], acc1[3][3]});
                u0.x = cvt_pk_bf16(p0[0], p0[1]);
                u0.y = cvt_pk_bf16(p1[0], p1[1]);
                u0.z = cvt_pk_bf16(p2[0], p2[1]);
                u0.w = cvt_pk_bf16(p3[0], p3[1]);
                u1.x = cvt_pk_bf16(p4[0], p4[1]);
                u1.y = cvt_pk_bf16(p5[0], p5[1]);
                u1.z = cvt_pk_bf16(p6[0], p6[1]);
                u1.w = cvt_pk_bf16(p7[0], p7[1]);
            }
            const bf16x8 bf0 = __builtin_bit_cast(bf16x8, u0);
            const bf16x8 bf1 = __builtin_bit_cast(bf16x8, u1);

            // layer-2: 4 tiles x 2 MFMA; lrelu + pack -> head B fragments
            uint4 v0, v1;
#pragma unroll
            for (int mt = 0; mt < 4; ++mt) {
                f32x4 acc = b2v[mt];                // permuted bias pre-load
                acc = __builtin_amdgcn_mfma_f32_16x16x32_bf16(afrag[mt][0], bf0, acc, 0, 0, 0);
                acc = __builtin_amdgcn_mfma_f32_16x16x32_bf16(afrag[mt][1], bf1, acc, 0, 0, 0);
                const f32x2 hlo = lrelu2((f32x2){acc[0], acc[1]});
                const f32x2 hhi = lrelu2((f32x2){acc[2], acc[3]});
                const unsigned pa = cvt_pk_bf16(hlo[0], hlo[1]);
                const unsigned pb = cvt_pk_bf16(hhi[0], hhi[1]);
                if (mt == 0)      { v0.x = pa; v0.y = pb; }
                else if (mt == 1) { v0.z = pa; v0.w = pb; }
                else if (mt == 2) { v1.x = pa; v1.y = pb; }
                else              { v1.z = pa; v1.w = pb; }
            }
            const bf16x8 bh0 = __builtin_bit_cast(bf16x8, v0);
            const bf16x8 bh1 = __builtin_bit_cast(bf16x8, v1);

            // heads: two parallel 2-MFMA chains (hi terms / lo terms)
            f32x4 ha = hinit;
            f32x4 hb = (f32x4){0.0f, 0.0f, 0.0f, 0.0f};
            ha = __builtin_amdgcn_mfma_f32_16x16x32_bf16(hA[0][0], bh0, ha, 0, 0, 0);
            hb = __builtin_amdgcn_mfma_f32_16x16x32_bf16(hA[0][1], bh0, hb, 0, 0, 0);
            ha = __builtin_amdgcn_mfma_f32_16x16x32_bf16(hA[1][0], bh1, ha, 0, 0, 0);
            hb = __builtin_amdgcn_mfma_f32_16x16x32_bf16(hA[1][1], bh1, hb, 0, 0, 0);

            // quad-0 lanes hold rows m=0,1,2 (Ld0, Ld1, Lo) for row it*16+c
            if (quad == 0) {
                const float ld0 = softplus(ha[0] + hb[0]);
                const float ld1 = softplus(ha[1] + hb[1]);
                const float lo  = ha[2] + hb[2];
                float4 o;
                o.x = fmaf(ld0, ld0, 1e-9f);                  // H00
                o.y = ld0 * lo;                               // H01
                o.z = o.y;                                    // H10
                o.w = fmaf(lo, lo, fmaf(ld1, ld1, 1e-9f));    // H11
                reinterpret_cast<float4*>(out)[wbase + it * 16 + c] = o;
            }
        }
    }
}

// ---- scalar fallback for tail rows (nrows % 256) --------------------------
__global__ __launch_bounds__(256) void dln_tail(
    const float* __restrict__ x,
    const float* __restrict__ W1,  const float* __restrict__ b1,
    const float* __restrict__ W2,  const float* __restrict__ b2,
    const float* __restrict__ WLd, const float* __restrict__ bLd,
    const float* __restrict__ WLo, const float* __restrict__ bLo,
    float* __restrict__ out, int row0, int nrows)
{
    const int row = row0 + blockIdx.x * 256 + threadIdx.x;
    if (row >= nrows) return;
    const float4 qv = reinterpret_cast<const float4*>(x)[row];
    float h1[64];
#pragma unroll
    for (int j = 0; j < 64; ++j) {
        float a = b1[j];
        a = fmaf(qv.x, W1[4 * j + 0], a);
        a = fmaf(qv.y, W1[4 * j + 1], a);
        a = fmaf(qv.z, W1[4 * j + 2], a);
        a = fmaf(qv.w, W1[4 * j + 3], a);
        h1[j] = lrelu(a);
    }
    float ld0 = bLd[0], ld1 = bLd[1], lo = bLo[0];
#pragma unroll 4
    for (int j = 0; j < 64; ++j) {
        float a0 = b2[j], a1 = 0.0f;
        const float* w = W2 + 64 * j;
#pragma unroll
        for (int k = 0; k < 64; k += 2) {
            a0 = fmaf(h1[k],     w[k],     a0);
            a1 = fmaf(h1[k + 1], w[k + 1], a1);
        }
        const float a = lrelu(a0 + a1);
        ld0 = fmaf(a, WLd[j],      ld0);
        ld1 = fmaf(a, WLd[64 + j], ld1);
        lo  = fmaf(a, WLo[j],      lo);
    }
    ld0 = softplus(ld0);
    ld1 = softplus(ld1);
    float4 o;
    o.x = fmaf(ld0, ld0, 1e-9f);
    o.y = ld0 * lo;
    o.z = o.y;
    o.w = fmaf(lo, lo, fmaf(ld1, ld1, 1e-9f));
    reinterpret_cast<float4*>(out)[row] = o;
}

extern "C" void kernel_launch(void* const* d_in, const int* in_sizes, int n_in,
                              void* d_out, int out_size, void* d_ws, size_t ws_size,
                              hipStream_t stream)
{
    const float* x   = (const float*)d_in[0];
    const float* W1  = (const float*)d_in[1];
    const float* b1  = (const float*)d_in[2];
    const float* W2  = (const float*)d_in[3];
    const float* b2  = (const float*)d_in[4];
    const float* WLd = (const float*)d_in[5];
    const float* bLd = (const float*)d_in[6];
    const float* WLo = (const float*)d_in[7];
    const float* bLo = (const float*)d_in[8];
    float* out = (float*)d_out;

    const int nrows   = in_sizes[0] / 4;            // x is (nrows, 4) fp32
    const int ngroups = nrows / ROWS_PER_GROUP;
    const int nfull   = ngroups * ROWS_PER_GROUP;
    const int rem     = nrows - nfull;

    if (ngroups > 0) {
        const int grid = (ngroups < GRID_BLOCKS) ? ngroups : GRID_BLOCKS;
        dln_mfma<<<grid, BLOCK_THREADS, 0, stream>>>(
            x, W1, b1, W2, b2, WLd, bLd, WLo, bLo, out, ngroups);
    }
    if (rem > 0)
        dln_tail<<<(rem + 255) / 256, 256, 0, stream>>>(
            x, W1, b1, W2, b2, WLd, bLd, WLo, bLo, out, nfull, nrows);
}

// Round 10
// 131.010 us; speedup vs baseline: 1.1262x; 1.0737x over previous
//
#include <hip/hip_runtime.h>

// ---------------------------------------------------------------------------
// DeepLagrangianNetwork head — round 14: all-MFMA + LDS weight tables + the
// 64-VGPR occupancy cliff (8 waves/SIMD, the one lever never pulled).
// Ledger: all 10 prior rounds ran at 3-4 waves/SIMD (VGPR 68-132) and landed
// 51-77 us despite ~9 us of pure issue -> latency-bound. This round designs
// live state < 64 and uses the empirical fact (R6/R8) that a launch_bounds
// second arg pins the allocator to exactly 64 VGPRs:
//   - a1 / afrag / b2v / hA fragments live in LDS tables (20 KiB), built
//     cooperatively once per block (one wave per table; formulas depend only
//     on consumer lane id) + one __syncthreads. Per-it ds_read_b128 at
//     16B/lane stride = conflict-free; register-pressure relief valve is a
//     cheap LDS re-read, not R11's VMEM remat.
//   - inner pipeline = R12/R13's VERIFIED all-MFMA math (folded 1-MFMA
//     layer-1, nu-permuted identity handoffs, MFMA heads; absmax exact
//     twice). One 256-row group per block, 4096 blocks.
// Permutation (verified R10-R13): nu(mt,m)=32*(mt>>1)+8*(m>>2)+4*(mt&1)+(m&3)
//   => lrelu'd C of tile mt, cvt_pk-packed, lands neuron k in k-slot k of the
//      next MFMA's B fragment (identity handoff, registers only).
// Layer-1 fold (verified R12): one 16x16x32 MFMA computes
//   W1hi*xhi + W1lo*xhi + W1hi*xlo + b1 via k-slot packing (residual ~2^-18).
// Fragment layouts (m89/m120-verified):
//   A[m=lane&15][k=(lane>>4)*8+j]   B[k=(lane>>4)*8+j][n=lane&15]
//   C: col(n)=lane&15, row(m)=(lane>>4)*4+reg
// ---------------------------------------------------------------------------

typedef __attribute__((ext_vector_type(8))) short bf16x8;
typedef __attribute__((ext_vector_type(4))) float f32x4;
typedef __attribute__((ext_vector_type(2))) float f32x2;

#define BLOCK_THREADS  256      // 4 waves; each wave owns 64 rows
#define ROWS_PER_GROUP 256

__device__ __forceinline__ float lrelu(float a) {
    return fmaxf(a, 0.01f * a);     // exact leaky_relu(0.01)
}

__device__ __forceinline__ f32x2 lrelu2(f32x2 a) {
    return __builtin_elementwise_max(a, a * 0.01f);
}

__device__ __forceinline__ float softplus(float v) {
    return fmaxf(v, 0.0f) + log1pf(expf(-fabsf(v)));   // jax.nn.softplus
}

// two fp32 -> packed bf16x2 (hardware RNE), 1 VALU op.
__device__ __forceinline__ unsigned cvt_pk_bf16(float lo, float hi) {
    unsigned r;
    asm("v_cvt_pk_bf16_f32 %0, %1, %2" : "=v"(r) : "v"(lo), "v"(hi));
    return r;
}

// residual v - float(bf16_hi(v)), where pk holds the packed hi pair
__device__ __forceinline__ float lo_of(float v, unsigned pk, bool hi_half) {
    const float h = __uint_as_float(hi_half ? (pk & 0xFFFF0000u) : (pk << 16));
    return v - h;
}

__global__ __launch_bounds__(BLOCK_THREADS, 4) void dln_mfma(
    const float* __restrict__ x,
    const float* __restrict__ W1,  const float* __restrict__ b1,
    const float* __restrict__ W2,  const float* __restrict__ b2,
    const float* __restrict__ WLd, const float* __restrict__ bLd,
    const float* __restrict__ WLo, const float* __restrict__ bLo,
    float* __restrict__ out)
{
    // weight-fragment tables, indexed by consumer lane: 20 KiB total
    __shared__ __align__(16) uint4  a1L[4][64];        // layer-1 A   (4 KiB)
    __shared__ __align__(16) uint4  afL[4][2][64];     // layer-2 A   (8 KiB)
    __shared__ __align__(16) float4 b2L[4][64];        // b2 (f32x4)  (4 KiB)
    __shared__ __align__(16) uint4  hAL[2][2][64];     // head A      (4 KiB)

    const int tid  = threadIdx.x;
    const int lane = tid & 63;
    const int wv   = tid >> 6;          // wave id 0..3
    const int quad = lane >> 4;         // 0..3
    const int c    = lane & 15;         // 0..15

    const int wbase = blockIdx.x * ROWS_PER_GROUP + wv * 64;

    // ---- x loads first (cold HBM): 4 independent float4 in flight --------
    float4 xv[4];
#pragma unroll
    for (int it = 0; it < 4; ++it)
        xv[it] = ((const float4*)x)[wbase + it * 16 + c];

    // ---- cooperative table build: one wave per table, consumer lane = lane
    if (wv == 0) {
        // layer-1 A: folded {W1hi, W1lo, b1hi, b1lo}; plus b2 (f32, permuted)
#pragma unroll
        for (int mt = 0; mt < 4; ++mt) {
            const int nu = 32 * (mt >> 1) + 8 * (c >> 2) + 4 * (mt & 1) + (c & 3);
            const float4 w = *(const float4*)(W1 + 4 * nu);
            const float bb = b1[nu];
            const unsigned h01 = cvt_pk_bf16(w.x, w.y);
            const unsigned h23 = cvt_pk_bf16(w.z, w.w);
            uint4 u = make_uint4(0u, 0u, 0u, 0u);
            if (quad == 0) {
                const unsigned t = cvt_pk_bf16(bb, 0.0f);
                const float bl = bb - __uint_as_float(t << 16);
                u.x = h01; u.y = h23;
                u.z = cvt_pk_bf16(bb, bl);          // k4=b1hi, k5=b1lo
            } else if (quad == 1) {
                u.x = cvt_pk_bf16(lo_of(w.x, h01, false), lo_of(w.y, h01, true));
                u.y = cvt_pk_bf16(lo_of(w.z, h23, false), lo_of(w.w, h23, true));
                u.z = h01; u.w = h23;               // k8-11=W1lo, k12-15=W1hi
            }
            a1L[mt][lane] = u;
            b2L[mt][lane] = *(const float4*)(b2 + 32 * (mt >> 1) + 4 * (mt & 1) + 8 * quad);
        }
    } else if (wv == 1 || wv == 2) {
        // layer-2 A: nu-permuted W2 rows, bf16
        const int mt0 = (wv == 1) ? 0 : 2;
#pragma unroll
        for (int k = 0; k < 2; ++k) {
            const int mt = mt0 + k;
            const int nu = 32 * (mt >> 1) + 8 * (c >> 2) + 4 * (mt & 1) + (c & 3);
            const float* wr = W2 + nu * 64 + 8 * quad;
#pragma unroll
            for (int s = 0; s < 2; ++s) {
                const float4 f0 = *(const float4*)(wr + 32 * s);
                const float4 f1 = *(const float4*)(wr + 32 * s + 4);
                uint4 u;
                u.x = cvt_pk_bf16(f0.x, f0.y);
                u.y = cvt_pk_bf16(f0.z, f0.w);
                u.z = cvt_pk_bf16(f1.x, f1.y);
                u.w = cvt_pk_bf16(f1.z, f1.w);
                afL[mt][s][lane] = u;
            }
        }
    } else {
        // head A: rows {WLd0, WLd1, WLo, 0...}, hi/lo split
        const float* hw = (c == 0) ? WLd : (c == 1) ? (WLd + 64) : WLo;
#pragma unroll
        for (int s = 0; s < 2; ++s) {
            uint4 uh = make_uint4(0u, 0u, 0u, 0u);
            uint4 ul = make_uint4(0u, 0u, 0u, 0u);
            if (c < 3) {
                const float* p = hw + 32 * s + 8 * quad;
                const float4 f0 = *(const float4*)(p);
                const float4 f1 = *(const float4*)(p + 4);
                uh.x = cvt_pk_bf16(f0.x, f0.y);
                uh.y = cvt_pk_bf16(f0.z, f0.w);
                uh.z = cvt_pk_bf16(f1.x, f1.y);
                uh.w = cvt_pk_bf16(f1.z, f1.w);
                ul.x = cvt_pk_bf16(lo_of(f0.x, uh.x, false), lo_of(f0.y, uh.x, true));
                ul.y = cvt_pk_bf16(lo_of(f0.z, uh.y, false), lo_of(f0.w, uh.y, true));
                ul.z = cvt_pk_bf16(lo_of(f1.x, uh.z, false), lo_of(f1.y, uh.z, true));
                ul.w = cvt_pk_bf16(lo_of(f1.z, uh.w, false), lo_of(f1.w, uh.w, true));
            }
            hAL[s][0][lane] = uh;
            hAL[s][1][lane] = ul;
        }
    }
    __syncthreads();

    const f32x4 hinit = (quad == 0)
        ? (f32x4){bLd[0], bLd[1], bLo[0], 0.0f}
        : (f32x4){0.0f, 0.0f, 0.0f, 0.0f};

    // ---- 4 independent row-tiles: L1 MFMA -> L2 MFMA -> head MFMA --------
#pragma unroll
    for (int it = 0; it < 4; ++it) {
        // layer-1 B fragment: folded {xhi, 1.0, xlo} per quad
        const unsigned xh01 = cvt_pk_bf16(xv[it].x, xv[it].y);
        const unsigned xh23 = cvt_pk_bf16(xv[it].z, xv[it].w);
        uint4 ub = make_uint4(0u, 0u, 0u, 0u);
        if (quad == 0) {
            ub.x = xh01; ub.y = xh23; ub.z = 0x3F803F80u;   // k4=k5=1.0
        } else if (quad == 1) {
            ub.x = xh01; ub.y = xh23;
            ub.z = cvt_pk_bf16(lo_of(xv[it].x, xh01, false), lo_of(xv[it].y, xh01, true));
            ub.w = cvt_pk_bf16(lo_of(xv[it].z, xh23, false), lo_of(xv[it].w, xh23, true));
        }
        const bf16x8 bx = __builtin_bit_cast(bf16x8, ub);

        // layer-1: one MFMA per tile, fragments from LDS
        f32x4 acc1[4];
#pragma unroll
        for (int mt = 0; mt < 4; ++mt) {
            const bf16x8 a1f = __builtin_bit_cast(bf16x8, a1L[mt][lane]);
            acc1[mt] = __builtin_amdgcn_mfma_f32_16x16x32_bf16(
                a1f, bx, (f32x4){0.0f, 0.0f, 0.0f, 0.0f}, 0, 0, 0);
        }

        // lrelu + pack: identity handoff to layer-2 B fragments
        uint4 u0, u1;
        {
            const f32x2 p0 = lrelu2((f32x2){acc1[0][0], acc1[0][1]});
            const f32x2 p1 = lrelu2((f32x2){acc1[0][2], acc1[0][3]});
            const f32x2 p2 = lrelu2((f32x2){acc1[1][0], acc1[1][1]});
            const f32x2 p3 = lrelu2((f32x2){acc1[1][2], acc1[1][3]});
            const f32x2 p4 = lrelu2((f32x2){acc1[2][0], acc1[2][1]});
            const f32x2 p5 = lrelu2((f32x2){acc1[2][2], acc1[2][3]});
            const f32x2 p6 = lrelu2((f32x2){acc1[3][0], acc1[3][1]});
            const f32x2 p7 = lrelu2((f32x2){acc1[3][2], acc1[3][3]});
            u0.x = cvt_pk_bf16(p0[0], p0[1]);
            u0.y = cvt_pk_bf16(p1[0], p1[1]);
            u0.z = cvt_pk_bf16(p2[0], p2[1]);
            u0.w = cvt_pk_bf16(p3[0], p3[1]);
            u1.x = cvt_pk_bf16(p4[0], p4[1]);
            u1.y = cvt_pk_bf16(p5[0], p5[1]);
            u1.z = cvt_pk_bf16(p6[0], p6[1]);
            u1.w = cvt_pk_bf16(p7[0], p7[1]);
        }
        const bf16x8 bf0 = __builtin_bit_cast(bf16x8, u0);
        const bf16x8 bf1 = __builtin_bit_cast(bf16x8, u1);

        // layer-2: 4 tiles x 2 MFMA (A + bias from LDS); pack -> head B
        uint4 v0, v1;
#pragma unroll
        for (int mt = 0; mt < 4; ++mt) {
            const float4 bb = b2L[mt][lane];
            f32x4 acc = (f32x4){bb.x, bb.y, bb.z, bb.w};
            const bf16x8 af0 = __builtin_bit_cast(bf16x8, afL[mt][0][lane]);
            const bf16x8 af1 = __builtin_bit_cast(bf16x8, afL[mt][1][lane]);
            acc = __builtin_amdgcn_mfma_f32_16x16x32_bf16(af0, bf0, acc, 0, 0, 0);
            acc = __builtin_amdgcn_mfma_f32_16x16x32_bf16(af1, bf1, acc, 0, 0, 0);
            const f32x2 hlo = lrelu2((f32x2){acc[0], acc[1]});
            const f32x2 hhi = lrelu2((f32x2){acc[2], acc[3]});
            const unsigned pa = cvt_pk_bf16(hlo[0], hlo[1]);
            const unsigned pb = cvt_pk_bf16(hhi[0], hhi[1]);
            if (mt == 0)      { v0.x = pa; v0.y = pb; }
            else if (mt == 1) { v0.z = pa; v0.w = pb; }
            else if (mt == 2) { v1.x = pa; v1.y = pb; }
            else              { v1.z = pa; v1.w = pb; }
        }
        const bf16x8 bh0 = __builtin_bit_cast(bf16x8, v0);
        const bf16x8 bh1 = __builtin_bit_cast(bf16x8, v1);

        // heads: two parallel 2-MFMA chains (hi terms / lo terms), A from LDS
        f32x4 ha = hinit;
        f32x4 hb = (f32x4){0.0f, 0.0f, 0.0f, 0.0f};
        {
            const bf16x8 h00 = __builtin_bit_cast(bf16x8, hAL[0][0][lane]);
            const bf16x8 h01 = __builtin_bit_cast(bf16x8, hAL[0][1][lane]);
            const bf16x8 h10 = __builtin_bit_cast(bf16x8, hAL[1][0][lane]);
            const bf16x8 h11 = __builtin_bit_cast(bf16x8, hAL[1][1][lane]);
            ha = __builtin_amdgcn_mfma_f32_16x16x32_bf16(h00, bh0, ha, 0, 0, 0);
            hb = __builtin_amdgcn_mfma_f32_16x16x32_bf16(h01, bh0, hb, 0, 0, 0);
            ha = __builtin_amdgcn_mfma_f32_16x16x32_bf16(h10, bh1, ha, 0, 0, 0);
            hb = __builtin_amdgcn_mfma_f32_16x16x32_bf16(h11, bh1, hb, 0, 0, 0);
        }

        // quad-0 lanes hold rows m=0,1,2 (Ld0, Ld1, Lo) for batch row it*16+c
        if (quad == 0) {
            const float ld0 = softplus(ha[0] + hb[0]);
            const float ld1 = softplus(ha[1] + hb[1]);
            const float lo  = ha[2] + hb[2];
            float4 o;
            o.x = fmaf(ld0, ld0, 1e-9f);                  // H00
            o.y = ld0 * lo;                               // H01
            o.z = o.y;                                    // H10
            o.w = fmaf(lo, lo, fmaf(ld1, ld1, 1e-9f));    // H11
            reinterpret_cast<float4*>(out)[wbase + it * 16 + c] = o;
        }
    }
}

// ---- scalar fallback for tail rows (nrows % 256) --------------------------
__global__ __launch_bounds__(256) void dln_tail(
    const float* __restrict__ x,
    const float* __restrict__ W1,  const float* __restrict__ b1,
    const float* __restrict__ W2,  const float* __restrict__ b2,
    const float* __restrict__ WLd, const float* __restrict__ bLd,
    const float* __restrict__ WLo, const float* __restrict__ bLo,
    float* __restrict__ out, int row0, int nrows)
{
    const int row = row0 + blockIdx.x * 256 + threadIdx.x;
    if (row >= nrows) return;
    const float4 qv = reinterpret_cast<const float4*>(x)[row];
    float h1[64];
#pragma unroll
    for (int j = 0; j < 64; ++j) {
        float a = b1[j];
        a = fmaf(qv.x, W1[4 * j + 0], a);
        a = fmaf(qv.y, W1[4 * j + 1], a);
        a = fmaf(qv.z, W1[4 * j + 2], a);
        a = fmaf(qv.w, W1[4 * j + 3], a);
        h1[j] = lrelu(a);
    }
    float ld0 = bLd[0], ld1 = bLd[1], lo = bLo[0];
#pragma unroll 4
    for (int j = 0; j < 64; ++j) {
        float a0 = b2[j], a1 = 0.0f;
        const float* w = W2 + 64 * j;
#pragma unroll
        for (int k = 0; k < 64; k += 2) {
            a0 = fmaf(h1[k],     w[k],     a0);
            a1 = fmaf(h1[k + 1], w[k + 1], a1);
        }
        const float a = lrelu(a0 + a1);
        ld0 = fmaf(a, WLd[j],      ld0);
        ld1 = fmaf(a, WLd[64 + j], ld1);
        lo  = fmaf(a, WLo[j],      lo);
    }
    ld0 = softplus(ld0);
    ld1 = softplus(ld1);
    float4 o;
    o.x = fmaf(ld0, ld0, 1e-9f);
    o.y = ld0 * lo;
    o.z = o.y;
    o.w = fmaf(lo, lo, fmaf(ld1, ld1, 1e-9f));
    reinterpret_cast<float4*>(out)[row] = o;
}

extern "C" void kernel_launch(void* const* d_in, const int* in_sizes, int n_in,
                              void* d_out, int out_size, void* d_ws, size_t ws_size,
                              hipStream_t stream)
{
    const float* x   = (const float*)d_in[0];
    const float* W1  = (const float*)d_in[1];
    const float* b1  = (const float*)d_in[2];
    const float* W2  = (const float*)d_in[3];
    const float* b2  = (const float*)d_in[4];
    const float* WLd = (const float*)d_in[5];
    const float* bLd = (const float*)d_in[6];
    const float* WLo = (const float*)d_in[7];
    const float* bLo = (const float*)d_in[8];
    float* out = (float*)d_out;

    const int nrows   = in_sizes[0] / 4;            // x is (nrows, 4) fp32
    const int ngroups = nrows / ROWS_PER_GROUP;
    const int nfull   = ngroups * ROWS_PER_GROUP;
    const int rem     = nrows - nfull;

    if (ngroups > 0)
        dln_mfma<<<ngroups, BLOCK_THREADS, 0, stream>>>(
            x, W1, b1, W2, b2, WLd, bLd, WLo, bLo, out);
    if (rem > 0)
        dln_tail<<<(rem + 255) / 256, 256, 0, stream>>>(
            x, W1, b1, W2, b2, WLd, bLd, WLo, bLo, out, nfull, nrows);
}

// Round 11
// 121.409 us; speedup vs baseline: 1.2153x; 1.0791x over previous
//
#include <hip/hip_runtime.h>

// ---------------------------------------------------------------------------
// DeepLagrangianNetwork head, MFMA version — FINAL (restored round-9 champion,
// 51.5 us/dispatch, the session best; verbatim).
// Session falsification ledger (12 structures, 51-77 us all):
//   - VALU-count (R5 -40% issue: no change), wg-turnover (R9 persistent: +6%),
//     remat/spill (R7/R13: neutral), all-MFMA pipelines (R12-14: equal/worse),
//     occupancy (R14: 24->63%, no gain), memory (LLC-hot dispatches with half
//     the HBM traffic time identically), bank conflicts 0 since R5.
//   - Compiler rules learned: __launch_bounds__ min-waves clause clamps to
//     64 VGPR and spills (R6/R8); grid-stride + lean allocation remats weight
//     prep (R11); asm pins add more issue than they save (R13).
// Structure: persistent blocks. grid = 1024 (4 blocks/CU, single generation),
// each block loops 4 iterations x 256 rows (stripe = 262144 rows) with
// software-pipelined x prefetch. Zero __syncthreads (wave-self-contained;
// LDS reuse across iterations is safe: per-wave DS ops execute in order).
// Per row: h1 = lrelu(q@W1^T+b1)  (4->64, VALU, v_cvt_pk_bf16 packing)
//          h2^T = W2 @ h1^T       (bf16 MFMA 16x16x32, A = W2 tiles)
//          heads (Ld, Lo) on fp32 h2 in-register (packed v_pk_fma_f32),
//          quad-reduced via shfl_xor; H = L L^T + 1e-9 I, float4/row store.
// Fragment layouts (m89/m120-verified):
//   A[m=lane&15][k=(lane>>4)*8+j]   B[k=(lane>>4)*8+j][n=lane&15]
//   C: col(n)=lane&15, row(m)=(lane>>4)*4+reg
//   mfma(Xf,Yf) = X.Y^T; X=W2 m-tile, Y=h1 row-tile => C[m=neuron][n=row].
// ---------------------------------------------------------------------------

typedef __attribute__((ext_vector_type(8))) short bf16x8;
typedef __attribute__((ext_vector_type(4))) float f32x4;
typedef __attribute__((ext_vector_type(2))) float f32x2;

#define BLOCK_THREADS 256       // 4 waves
#define GRID_BLOCKS   1024      // 4 blocks/CU on 256 CUs — single generation

__device__ __forceinline__ float lrelu(float a) {
    return fmaxf(a, 0.01f * a);     // exact leaky_relu(0.01)
}

__device__ __forceinline__ f32x2 lrelu2(f32x2 a) {
    return __builtin_elementwise_max(a, a * 0.01f);   // v_pk_mul + v_pk_max
}

__device__ __forceinline__ float softplus(float v) {
    return fmaxf(v, 0.0f) + log1pf(expf(-fabsf(v)));   // jax.nn.softplus
}

// two fp32 -> packed bf16x2 (hardware RNE), 1 VALU op.
__device__ __forceinline__ unsigned cvt_pk_bf16(float lo, float hi) {
    unsigned r;
    asm("v_cvt_pk_bf16_f32 %0, %1, %2" : "=v"(r) : "v"(lo), "v"(hi));
    return r;
}

__global__ __launch_bounds__(BLOCK_THREADS) void dln_mfma(
    const float* __restrict__ x,
    const float* __restrict__ W1,  const float* __restrict__ b1,
    const float* __restrict__ W2,  const float* __restrict__ b2,
    const float* __restrict__ WLd, const float* __restrict__ bLd,
    const float* __restrict__ WLo, const float* __restrict__ bLo,
    float* __restrict__ out,
    int iters, int iter_stride)
{
    __shared__ __align__(16) unsigned short h1s[4][8][64][8];   // 32 KiB

    const int tid  = threadIdx.x;
    const int lane = tid & 63;
    const int wv   = tid >> 6;          // wave id 0..3
    const int quad = lane >> 4;         // 0..3
    const int c    = lane & 15;         // 0..15

    // ---- first x load in flight before anything else ----------------------
    int row = blockIdx.x * BLOCK_THREADS + tid;
    float4 qnext = ((const float4*)x)[row];

    // ---- preload (once per block, amortized over `iters` stripes):
    //      A-frags = W2 tiles (bf16), head weights + b2 (fp32, lane-indexed)
    bf16x8 afrag[4][2];
    f32x4 wld0[4], wld1[4], wlo[4], b2v[4];
#pragma unroll
    for (int mt = 0; mt < 4; ++mt) {
        const float* wr = W2 + (16 * mt + c) * 64 + 8 * quad;
#pragma unroll
        for (int s = 0; s < 2; ++s) {
            const float4 f0 = *(const float4*)(wr + 32 * s);
            const float4 f1 = *(const float4*)(wr + 32 * s + 4);
            uint4 u;
            u.x = cvt_pk_bf16(f0.x, f0.y);
            u.y = cvt_pk_bf16(f0.z, f0.w);
            u.z = cvt_pk_bf16(f1.x, f1.y);
            u.w = cvt_pk_bf16(f1.z, f1.w);
            afrag[mt][s] = __builtin_bit_cast(bf16x8, u);
        }
        const int nb = 16 * mt + 4 * quad;   // this lane's 16 neurons
        wld0[mt] = *(const f32x4*)(WLd + nb);
        wld1[mt] = *(const f32x4*)(WLd + 64 + nb);
        wlo[mt]  = *(const f32x4*)(WLo + nb);
        b2v[mt]  = *(const f32x4*)(b2 + nb);
    }
    const float bld0 = bLd[0];
    const float bld1 = bLd[1];
    const float blo0 = bLo[0];

    for (int itr = 0; itr < iters; ++itr) {
        const float4 qv = qnext;
        const int row_cur = row;
        row += iter_stride;
        if (itr + 1 < iters)                 // uniform branch
            qnext = ((const float4*)x)[row]; // prefetch next stripe

        // ---- phase 1: h1 = lrelu(q@W1^T + b1), bf16 -> LDS (own slot) ----
#pragma unroll
        for (int ch = 0; ch < 8; ++ch) {        // chunk ch holds k=8ch..8ch+7
            unsigned up[4];
#pragma unroll
            for (int p = 0; p < 4; ++p) {
                float h[2];
#pragma unroll
                for (int e = 0; e < 2; ++e) {
                    const int j = ch * 8 + p * 2 + e;
                    float a = b1[j];
                    a = fmaf(qv.x, W1[4 * j + 0], a);
                    a = fmaf(qv.y, W1[4 * j + 1], a);
                    a = fmaf(qv.z, W1[4 * j + 2], a);
                    a = fmaf(qv.w, W1[4 * j + 3], a);
                    h[e] = lrelu(a);
                }
                up[p] = cvt_pk_bf16(h[0], h[1]);
            }
            *(uint4*)&h1s[wv][ch][lane][0] = make_uint4(up[0], up[1], up[2], up[3]);
        }
        // No barrier: this wave reads only rows it wrote; per-wave DS ops
        // execute in order (also makes buffer reuse across iterations safe).

        // ---- phase 2: h2^T tiles via MFMA; heads in-register (pk math) ---
        float sld0 = 0.0f, sld1 = 0.0f, slo = 0.0f;
#pragma unroll
        for (int it = 0; it < 4; ++it) {            // 16 batch rows / iter
            const bf16x8 bf0 = *(const bf16x8*)&h1s[wv][quad][it * 16 + c][0];
            const bf16x8 bf1 = *(const bf16x8*)&h1s[wv][4 + quad][it * 16 + c][0];

            f32x2 pld0 = {0.0f, 0.0f}, pld1 = {0.0f, 0.0f}, plo = {0.0f, 0.0f};
#pragma unroll
            for (int mt = 0; mt < 4; ++mt) {
                f32x4 acc = b2v[mt];                // bias pre-load
                acc = __builtin_amdgcn_mfma_f32_16x16x32_bf16(afrag[mt][0], bf0, acc, 0, 0, 0);
                acc = __builtin_amdgcn_mfma_f32_16x16x32_bf16(afrag[mt][1], bf1, acc, 0, 0, 0);
                // acc[r] = pre-act h2[row it*16+c][neuron 16mt+4quad+r]
                const f32x2 hlo = lrelu2((f32x2){acc[0], acc[1]});
                const f32x2 hhi = lrelu2((f32x2){acc[2], acc[3]});
                pld0 = __builtin_elementwise_fma(hlo, (f32x2){wld0[mt][0], wld0[mt][1]}, pld0);
                pld0 = __builtin_elementwise_fma(hhi, (f32x2){wld0[mt][2], wld0[mt][3]}, pld0);
                pld1 = __builtin_elementwise_fma(hlo, (f32x2){wld1[mt][0], wld1[mt][1]}, pld1);
                pld1 = __builtin_elementwise_fma(hhi, (f32x2){wld1[mt][2], wld1[mt][3]}, pld1);
                plo  = __builtin_elementwise_fma(hlo, (f32x2){wlo[mt][0],  wlo[mt][1]},  plo);
                plo  = __builtin_elementwise_fma(hhi, (f32x2){wlo[mt][2],  wlo[mt][3]},  plo);
            }
            // horizontal add of the pk pairs, then reduce over the 4 quads
            float r0 = pld0[0] + pld0[1];
            float r1 = pld1[0] + pld1[1];
            float r2 = plo[0]  + plo[1];
            r0 += __shfl_xor(r0, 16); r0 += __shfl_xor(r0, 32);
            r1 += __shfl_xor(r1, 16); r1 += __shfl_xor(r1, 32);
            r2 += __shfl_xor(r2, 16); r2 += __shfl_xor(r2, 32);
            // lane(q,c) keeps iteration it==q -> its own row (= lane)
            if (it == quad) { sld0 = r0; sld1 = r1; slo = r2; }
        }

        // ---- epilogue: one row per lane, fully coalesced store -----------
        {
            const float ld0 = softplus(sld0 + bld0);
            const float ld1 = softplus(sld1 + bld1);
            const float lo  = slo + blo0;
            float4 o;
            o.x = fmaf(ld0, ld0, 1e-9f);                  // H00
            o.y = ld0 * lo;                               // H01
            o.z = o.y;                                    // H10
            o.w = fmaf(lo, lo, fmaf(ld1, ld1, 1e-9f));    // H11
            reinterpret_cast<float4*>(out)[row_cur] = o;
        }
    }
}

// ---- scalar fallback for tail rows ----------------------------------------
__global__ __launch_bounds__(256) void dln_tail(
    const float* __restrict__ x,
    const float* __restrict__ W1,  const float* __restrict__ b1,
    const float* __restrict__ W2,  const float* __restrict__ b2,
    const float* __restrict__ WLd, const float* __restrict__ bLd,
    const float* __restrict__ WLo, const float* __restrict__ bLo,
    float* __restrict__ out, int row0, int nrows)
{
    const int row = row0 + blockIdx.x * 256 + threadIdx.x;
    if (row >= nrows) return;
    const float4 qv = reinterpret_cast<const float4*>(x)[row];
    float h1[64];
#pragma unroll
    for (int j = 0; j < 64; ++j) {
        float a = b1[j];
        a = fmaf(qv.x, W1[4 * j + 0], a);
        a = fmaf(qv.y, W1[4 * j + 1], a);
        a = fmaf(qv.z, W1[4 * j + 2], a);
        a = fmaf(qv.w, W1[4 * j + 3], a);
        h1[j] = lrelu(a);
    }
    float ld0 = bLd[0], ld1 = bLd[1], lo = bLo[0];
#pragma unroll 4
    for (int j = 0; j < 64; ++j) {
        float a0 = b2[j], a1 = 0.0f;
        const float* w = W2 + 64 * j;
#pragma unroll
        for (int k = 0; k < 64; k += 2) {
            a0 = fmaf(h1[k],     w[k],     a0);
            a1 = fmaf(h1[k + 1], w[k + 1], a1);
        }
        const float a = lrelu(a0 + a1);
        ld0 = fmaf(a, WLd[j],      ld0);
        ld1 = fmaf(a, WLd[64 + j], ld1);
        lo  = fmaf(a, WLo[j],      lo);
    }
    ld0 = softplus(ld0);
    ld1 = softplus(ld1);
    float4 o;
    o.x = fmaf(ld0, ld0, 1e-9f);
    o.y = ld0 * lo;
    o.z = o.y;
    o.w = fmaf(lo, lo, fmaf(ld1, ld1, 1e-9f));
    reinterpret_cast<float4*>(out)[row] = o;
}

extern "C" void kernel_launch(void* const* d_in, const int* in_sizes, int n_in,
                              void* d_out, int out_size, void* d_ws, size_t ws_size,
                              hipStream_t stream)
{
    const float* x   = (const float*)d_in[0];
    const float* W1  = (const float*)d_in[1];
    const float* b1  = (const float*)d_in[2];
    const float* W2  = (const float*)d_in[3];
    const float* b2  = (const float*)d_in[4];
    const float* WLd = (const float*)d_in[5];
    const float* bLd = (const float*)d_in[6];
    const float* WLo = (const float*)d_in[7];
    const float* bLo = (const float*)d_in[8];
    float* out = (float*)d_out;

    const int nrows  = in_sizes[0] / 4;             // x is (nrows, 4) fp32
    const int stripe = GRID_BLOCKS * BLOCK_THREADS; // 262144 rows / stripe
    const int iters  = nrows / stripe;
    const int nfull  = iters * stripe;
    const int rem    = nrows - nfull;

    if (iters > 0)
        dln_mfma<<<GRID_BLOCKS, BLOCK_THREADS, 0, stream>>>(
            x, W1, b1, W2, b2, WLd, bLd, WLo, bLo, out, iters, stripe);
    if (rem > 0)
        dln_tail<<<(rem + 255) / 256, 256, 0, stream>>>(
            x, W1, b1, W2, b2, WLd, bLd, WLo, bLo, out, nfull, nrows);
}

// Round 12
// 120.397 us; speedup vs baseline: 1.2255x; 1.0084x over previous
//
#include <hip/hip_runtime.h>

// ---------------------------------------------------------------------------
// DeepLagrangianNetwork head — round 16: champion (R9) + ONE change:
// phase-1 W1/b1 weights read from LDS (broadcast) instead of scalar loads.
// Theory under test (last untested): SMEM completes OUT-OF-ORDER, so every
// s_load use forces s_waitcnt lgkmcnt(0) — draining all outstanding DS ops
// too (shared counter). 320 uniform floats don't fit the SGPR file
// (SGPR_Count was 112 = maxed), so the compiler re-issues the s_load chains
// every iteration, each use a full drain, all 4 lockstep waves stalling
// together. LDS reads are IN-ORDER -> precise counted lgkmcnt(N) waits.
// The staging is per-wave (1.25 KiB x 4 = 5 KiB) so the kernel stays
// zero-barrier / wave-self-contained. Arithmetic order bit-identical.
// Everything else verbatim from the champion:
//   persistent 1024 blocks (4/CU, 37 KiB LDS -> still 4 blocks/CU), 4 its
//   x 256 rows, software-pipelined x prefetch, phase-1 VALU h1 -> LDS bf16,
//   phase-2 MFMA (A = W2 tiles), heads in-register (pk fma), quad shfl_xor
//   reduce, H = L L^T + 1e-9 I.
// Fragment layouts (m89/m120-verified):
//   A[m=lane&15][k=(lane>>4)*8+j]   B[k=(lane>>4)*8+j][n=lane&15]
//   C: col(n)=lane&15, row(m)=(lane>>4)*4+reg
// ---------------------------------------------------------------------------

typedef __attribute__((ext_vector_type(8))) short bf16x8;
typedef __attribute__((ext_vector_type(4))) float f32x4;
typedef __attribute__((ext_vector_type(2))) float f32x2;

#define BLOCK_THREADS 256       // 4 waves
#define GRID_BLOCKS   1024      // 4 blocks/CU on 256 CUs — single generation

__device__ __forceinline__ float lrelu(float a) {
    return fmaxf(a, 0.01f * a);     // exact leaky_relu(0.01)
}

__device__ __forceinline__ f32x2 lrelu2(f32x2 a) {
    return __builtin_elementwise_max(a, a * 0.01f);   // v_pk_mul + v_pk_max
}

__device__ __forceinline__ float softplus(float v) {
    return fmaxf(v, 0.0f) + log1pf(expf(-fabsf(v)));   // jax.nn.softplus
}

// two fp32 -> packed bf16x2 (hardware RNE), 1 VALU op.
__device__ __forceinline__ unsigned cvt_pk_bf16(float lo, float hi) {
    unsigned r;
    asm("v_cvt_pk_bf16_f32 %0, %1, %2" : "=v"(r) : "v"(lo), "v"(hi));
    return r;
}

__global__ __launch_bounds__(BLOCK_THREADS) void dln_mfma(
    const float* __restrict__ x,
    const float* __restrict__ W1,  const float* __restrict__ b1,
    const float* __restrict__ W2,  const float* __restrict__ b2,
    const float* __restrict__ WLd, const float* __restrict__ bLd,
    const float* __restrict__ WLo, const float* __restrict__ bLo,
    float* __restrict__ out,
    int iters, int iter_stride)
{
    __shared__ __align__(16) unsigned short h1s[4][8][64][8];   // 32 KiB
    __shared__ __align__(16) float w1s[4][320];                 // 5 KiB: W1|b1 per wave

    const int tid  = threadIdx.x;
    const int lane = tid & 63;
    const int wv   = tid >> 6;          // wave id 0..3
    const int quad = lane >> 4;         // 0..3
    const int c    = lane & 15;         // 0..15

    // ---- first x load in flight before anything else ----------------------
    int row = blockIdx.x * BLOCK_THREADS + tid;
    float4 qnext = ((const float4*)x)[row];

    // ---- stage W1 (256 f32) + b1 (64 f32) into this wave's LDS slot -------
    // per-wave copy -> no barrier needed anywhere (wave-self-contained).
#pragma unroll
    for (int i = 0; i < 4; ++i)
        w1s[wv][lane + 64 * i] = W1[lane + 64 * i];
    w1s[wv][256 + lane] = b1[lane];

    // ---- preload (once per block, amortized over `iters` stripes):
    //      A-frags = W2 tiles (bf16), head weights + b2 (fp32, lane-indexed)
    bf16x8 afrag[4][2];
    f32x4 wld0[4], wld1[4], wlo[4], b2v[4];
#pragma unroll
    for (int mt = 0; mt < 4; ++mt) {
        const float* wr = W2 + (16 * mt + c) * 64 + 8 * quad;
#pragma unroll
        for (int s = 0; s < 2; ++s) {
            const float4 f0 = *(const float4*)(wr + 32 * s);
            const float4 f1 = *(const float4*)(wr + 32 * s + 4);
            uint4 u;
            u.x = cvt_pk_bf16(f0.x, f0.y);
            u.y = cvt_pk_bf16(f0.z, f0.w);
            u.z = cvt_pk_bf16(f1.x, f1.y);
            u.w = cvt_pk_bf16(f1.z, f1.w);
            afrag[mt][s] = __builtin_bit_cast(bf16x8, u);
        }
        const int nb = 16 * mt + 4 * quad;   // this lane's 16 neurons
        wld0[mt] = *(const f32x4*)(WLd + nb);
        wld1[mt] = *(const f32x4*)(WLd + 64 + nb);
        wlo[mt]  = *(const f32x4*)(WLo + nb);
        b2v[mt]  = *(const f32x4*)(b2 + nb);
    }
    const float bld0 = bLd[0];
    const float bld1 = bLd[1];
    const float blo0 = bLo[0];

    for (int itr = 0; itr < iters; ++itr) {
        const float4 qv = qnext;
        const int row_cur = row;
        row += iter_stride;
        if (itr + 1 < iters)                 // uniform branch
            qnext = ((const float4*)x)[row]; // prefetch next stripe

        // ---- phase 1: h1 = lrelu(q@W1^T + b1), weights via LDS broadcast -
#pragma unroll
        for (int ch = 0; ch < 8; ++ch) {        // chunk ch holds k=8ch..8ch+7
            unsigned up[4];
#pragma unroll
            for (int p = 0; p < 4; ++p) {
                const int j0 = ch * 8 + p * 2;
                const float4 wA = *(const float4*)&w1s[wv][4 * j0];       // W1 row j0
                const float4 wB = *(const float4*)&w1s[wv][4 * j0 + 4];   // W1 row j0+1
                const float2 bb = *(const float2*)&w1s[wv][256 + j0];     // b1[j0..j0+1]
                // identical op order to champion: (((b + x*w0) + y*w1) + z*w2) + w*w3
                float a0 = bb.x;
                a0 = fmaf(qv.x, wA.x, a0);
                a0 = fmaf(qv.y, wA.y, a0);
                a0 = fmaf(qv.z, wA.z, a0);
                a0 = fmaf(qv.w, wA.w, a0);
                float a1 = bb.y;
                a1 = fmaf(qv.x, wB.x, a1);
                a1 = fmaf(qv.y, wB.y, a1);
                a1 = fmaf(qv.z, wB.z, a1);
                a1 = fmaf(qv.w, wB.w, a1);
                up[p] = cvt_pk_bf16(lrelu(a0), lrelu(a1));
            }
            *(uint4*)&h1s[wv][ch][lane][0] = make_uint4(up[0], up[1], up[2], up[3]);
        }
        // No barrier: this wave reads only rows it wrote; per-wave DS ops
        // execute in order (also makes buffer reuse across iterations safe).

        // ---- phase 2: h2^T tiles via MFMA; heads in-register (pk math) ---
        float sld0 = 0.0f, sld1 = 0.0f, slo = 0.0f;
#pragma unroll
        for (int it = 0; it < 4; ++it) {            // 16 batch rows / iter
            const bf16x8 bf0 = *(const bf16x8*)&h1s[wv][quad][it * 16 + c][0];
            const bf16x8 bf1 = *(const bf16x8*)&h1s[wv][4 + quad][it * 16 + c][0];

            f32x2 pld0 = {0.0f, 0.0f}, pld1 = {0.0f, 0.0f}, plo = {0.0f, 0.0f};
#pragma unroll
            for (int mt = 0; mt < 4; ++mt) {
                f32x4 acc = b2v[mt];                // bias pre-load
                acc = __builtin_amdgcn_mfma_f32_16x16x32_bf16(afrag[mt][0], bf0, acc, 0, 0, 0);
                acc = __builtin_amdgcn_mfma_f32_16x16x32_bf16(afrag[mt][1], bf1, acc, 0, 0, 0);
                // acc[r] = pre-act h2[row it*16+c][neuron 16mt+4quad+r]
                const f32x2 hlo = lrelu2((f32x2){acc[0], acc[1]});
                const f32x2 hhi = lrelu2((f32x2){acc[2], acc[3]});
                pld0 = __builtin_elementwise_fma(hlo, (f32x2){wld0[mt][0], wld0[mt][1]}, pld0);
                pld0 = __builtin_elementwise_fma(hhi, (f32x2){wld0[mt][2], wld0[mt][3]}, pld0);
                pld1 = __builtin_elementwise_fma(hlo, (f32x2){wld1[mt][0], wld1[mt][1]}, pld1);
                pld1 = __builtin_elementwise_fma(hhi, (f32x2){wld1[mt][2], wld1[mt][3]}, pld1);
                plo  = __builtin_elementwise_fma(hlo, (f32x2){wlo[mt][0],  wlo[mt][1]},  plo);
                plo  = __builtin_elementwise_fma(hhi, (f32x2){wlo[mt][2],  wlo[mt][3]},  plo);
            }
            // horizontal add of the pk pairs, then reduce over the 4 quads
            float r0 = pld0[0] + pld0[1];
            float r1 = pld1[0] + pld1[1];
            float r2 = plo[0]  + plo[1];
            r0 += __shfl_xor(r0, 16); r0 += __shfl_xor(r0, 32);
            r1 += __shfl_xor(r1, 16); r1 += __shfl_xor(r1, 32);
            r2 += __shfl_xor(r2, 16); r2 += __shfl_xor(r2, 32);
            // lane(q,c) keeps iteration it==q -> its own row (= lane)
            if (it == quad) { sld0 = r0; sld1 = r1; slo = r2; }
        }

        // ---- epilogue: one row per lane, fully coalesced store -----------
        {
            const float ld0 = softplus(sld0 + bld0);
            const float ld1 = softplus(sld1 + bld1);
            const float lo  = slo + blo0;
            float4 o;
            o.x = fmaf(ld0, ld0, 1e-9f);                  // H00
            o.y = ld0 * lo;                               // H01
            o.z = o.y;                                    // H10
            o.w = fmaf(lo, lo, fmaf(ld1, ld1, 1e-9f));    // H11
            reinterpret_cast<float4*>(out)[row_cur] = o;
        }
    }
}

// ---- scalar fallback for tail rows ----------------------------------------
__global__ __launch_bounds__(256) void dln_tail(
    const float* __restrict__ x,
    const float* __restrict__ W1,  const float* __restrict__ b1,
    const float* __restrict__ W2,  const float* __restrict__ b2,
    const float* __restrict__ WLd, const float* __restrict__ bLd,
    const float* __restrict__ WLo, const float* __restrict__ bLo,
    float* __restrict__ out, int row0, int nrows)
{
    const int row = row0 + blockIdx.x * 256 + threadIdx.x;
    if (row >= nrows) return;
    const float4 qv = reinterpret_cast<const float4*>(x)[row];
    float h1[64];
#pragma unroll
    for (int j = 0; j < 64; ++j) {
        float a = b1[j];
        a = fmaf(qv.x, W1[4 * j + 0], a);
        a = fmaf(qv.y, W1[4 * j + 1], a);
        a = fmaf(qv.z, W1[4 * j + 2], a);
        a = fmaf(qv.w, W1[4 * j + 3], a);
        h1[j] = lrelu(a);
    }
    float ld0 = bLd[0], ld1 = bLd[1], lo = bLo[0];
#pragma unroll 4
    for (int j = 0; j < 64; ++j) {
        float a0 = b2[j], a1 = 0.0f;
        const float* w = W2 + 64 * j;
#pragma unroll
        for (int k = 0; k < 64; k += 2) {
            a0 = fmaf(h1[k],     w[k],     a0);
            a1 = fmaf(h1[k + 1], w[k + 1], a1);
        }
        const float a = lrelu(a0 + a1);
        ld0 = fmaf(a, WLd[j],      ld0);
        ld1 = fmaf(a, WLd[64 + j], ld1);
        lo  = fmaf(a, WLo[j],      lo);
    }
    ld0 = softplus(ld0);
    ld1 = softplus(ld1);
    float4 o;
    o.x = fmaf(ld0, ld0, 1e-9f);
    o.y = ld0 * lo;
    o.z = o.y;
    o.w = fmaf(lo, lo, fmaf(ld1, ld1, 1e-9f));
    reinterpret_cast<float4*>(out)[row] = o;
}

extern "C" void kernel_launch(void* const* d_in, const int* in_sizes, int n_in,
                              void* d_out, int out_size, void* d_ws, size_t ws_size,
                              hipStream_t stream)
{
    const float* x   = (const float*)d_in[0];
    const float* W1  = (const float*)d_in[1];
    const float* b1  = (const float*)d_in[2];
    const float* W2  = (const float*)d_in[3];
    const float* b2  = (const float*)d_in[4];
    const float* WLd = (const float*)d_in[5];
    const float* bLd = (const float*)d_in[6];
    const float* WLo = (const float*)d_in[7];
    const float* bLo = (const float*)d_in[8];
    float* out = (float*)d_out;

    const int nrows  = in_sizes[0] / 4;             // x is (nrows, 4) fp32
    const int stripe = GRID_BLOCKS * BLOCK_THREADS; // 262144 rows / stripe
    const int iters  = nrows / stripe;
    const int nfull  = iters * stripe;
    const int rem    = nrows - nfull;

    if (iters > 0)
        dln_mfma<<<GRID_BLOCKS, BLOCK_THREADS, 0, stream>>>(
            x, W1, b1, W2, b2, WLd, bLd, WLo, bLo, out, iters, stripe);
    if (rem > 0)
        dln_tail<<<(rem + 255) / 256, 256, 0, stream>>>(
            x, W1, b1, W2, b2, WLd, bLd, WLo, bLo, out, nfull, nrows);
}